// Round 9
// baseline (10020.233 us; speedup 1.0000x reference)
//
#include <hip/hip_runtime.h>
#include <hip/hip_bf16.h>

// StackedMatchLSTM on MI355X — multi-CU scan, ONE LLC sync per step.
// B=32, TP=512, TQ=64, DP=DQ=H=AH=256, NL=2.
// 256 WGs (8 slices x 32 batches) x 512 threads. Slice j owns h-elems
// [32j,32j+32) and their 128 gate cols. Per step, slice j publishes its h
// slice AND its k-slice partial of hw_att = h @ W_att_r (256 f) in one
// release. Consumers poll once, gather h + 8 partials, sum -> full hw_att,
// then scores+softmax run fully locally (qWq bf16 in LDS).
// Sync: relaxed agent payload stores + per-slice RMW tag (release-add /
// relaxed add-0 spin) — the r5-r8-proven stable primitive.

#define NB 32
#define TPL 512
#define TQL 64
#define DD 256      // DP = DQ = H = AH
#define H4 1024     // 4*H
#define NC 1280     // AH + 4H
#define NS 8        // slices per batch
#define GC 128      // gate cols per slice
#define TAGSTR 16   // ints between tags (64 B)

__device__ __forceinline__ float fast_tanh(float x) {
  float xc = fminf(fmaxf(x, -9.f), 9.f);
  float e = __expf(2.f * xc);
  return (e - 1.f) * __builtin_amdgcn_rcpf(e + 1.f);
}
__device__ __forceinline__ float fast_sigmoid(float x) {
  return __builtin_amdgcn_rcpf(1.f + __expf(-x));
}
__device__ __forceinline__ float bflo(unsigned int w) { return __uint_as_float(w << 16); }
__device__ __forceinline__ float bfhi(unsigned int w) { return __uint_as_float(w & 0xffff0000u); }
__device__ __forceinline__ unsigned int packbf(float a, float b) {
  unsigned int lo = __hip_bfloat16_raw(__float2bfloat16(a)).x;
  unsigned int hi = __hip_bfloat16_raw(__float2bfloat16(b)).x;
  return lo | (hi << 16);
}

// ---- agent-scope sync: RMW-only (executes at LLC, stale-proof) --------------
__device__ __forceinline__ float aloadf(const float* p) {
  return __hip_atomic_load(p, __ATOMIC_RELAXED, __HIP_MEMORY_SCOPE_AGENT);
}
__device__ __forceinline__ void astoref(float* p, float v) {
  __hip_atomic_store(p, v, __ATOMIC_RELAXED, __HIP_MEMORY_SCOPE_AGENT);
}
__device__ __forceinline__ void radd(int* p) {
  __hip_atomic_fetch_add(p, 1, __ATOMIC_RELEASE, __HIP_MEMORY_SCOPE_AGENT);
}
__device__ __forceinline__ void spin_ge(int* p, int tgt) {
  int guard = 0;
  while (__hip_atomic_fetch_add(p, 0, __ATOMIC_RELAXED, __HIP_MEMORY_SCOPE_AGENT) < tgt) {
    __builtin_amdgcn_s_sleep(1);
    if (++guard > (1 << 26)) break;   // bail instead of hanging the harness
  }
}

// permuted xpl cols: [0,256) att (shared) | per slice j: 128 gate cols f|i|o|g
__device__ __forceinline__ int perm_col(int c) {
  if (c < DD) return c;
  int cc = c - DD;
  int g = cc >> 8;          // 0..3 = f,i,o,g
  int m = cc & 255;         // h-elem
  return DD + (m >> 5) * GC + (g << 5) + (m & 31);
}

// ---- weight prep ------------------------------------------------------------
__global__ __launch_bounds__(256) void pack_weights(
    const float* __restrict__ Wp, const float* __restrict__ Wq,
    const float* __restrict__ Wl,
    float* __restrict__ wx, float* __restrict__ wqv)
{
  int d = blockIdx.y;
  int idx = blockIdx.x * 256 + threadIdx.x;
  if (idx >= DD * NC) return;
  int k = idx / NC, j = idx % NC;
  int o = d * DD * NC + idx;
  const float* Wld = Wl + (size_t)d * 768 * H4;
  if (j < DD) {
    int s = d * DD * DD + k * DD + j;
    wx[o] = Wp[s]; wqv[o] = Wq[s];
  } else {
    int c = j - DD;
    wx[o]  = Wld[(size_t)k * H4 + c];
    wqv[o] = Wld[(size_t)(DD + k) * H4 + c];
  }
}

// attk[((d*8+j)*32 + k)*128 + aw]: uint = bf16 pair (Wr[d][32j+k][2aw], [2aw+1])
__global__ __launch_bounds__(256) void pack_attk(
    const float* __restrict__ Wr, unsigned int* __restrict__ attk)
{
  int idx = blockIdx.x * 256 + threadIdx.x;       // 2*8*32*128 = 65536
  if (idx >= 2 * NS * 32 * 128) return;
  int aw = idx & 127; int r = idx >> 7;
  int k = r & 31; r >>= 5;
  int j = r & 7; int d = r >> 3;
  const float* row = Wr + ((size_t)d * DD + (j << 5) + k) * DD;
  attk[idx] = packbf(row[2 * aw], row[2 * aw + 1]);
}

// gatel[((d*8+j)*32 + kq4)*128 + col]: uint4 = 8 k of Wl h-part col (g,j,pos)
__global__ __launch_bounds__(256) void pack_gatel(
    const float* __restrict__ Wl, uint4* __restrict__ gatel)
{
  int idx = blockIdx.x * 256 + threadIdx.x;       // 2*8*32*128 = 65536
  if (idx >= 2 * NS * 32 * GC) return;
  int col = idx & 127; int r = idx >> 7;
  int kq4 = r & 31; r >>= 5;
  int j = r & 7; int d = r >> 3;
  int g = col >> 5, pos = col & 31;
  float v[8];
  #pragma unroll
  for (int kr = 0; kr < 8; ++kr) {
    int k = kq4 * 8 + kr;
    v[kr] = Wl[((size_t)d * 768 + 512 + k) * H4 + (g << 8) + (j << 5) + pos];
  }
  gatel[idx] = make_uint4(packbf(v[0], v[1]), packbf(v[2], v[3]),
                          packbf(v[4], v[5]), packbf(v[6], v[7]));
}

// ---- C[M][1280] = A[M][256] @ B[256][1280], fp32 ----------------------------
template <bool PERM>
__global__ __launch_bounds__(256) void sgemm(
    const float* __restrict__ A, const float* __restrict__ Bm,
    float* __restrict__ C)
{
  __shared__ float As[16][65];
  __shared__ float Bs[16][64];
  int tid = threadIdx.x;
  int tx = tid & 15, ty = tid >> 4;
  int col0 = blockIdx.x * 64, row0 = blockIdx.y * 64;
  float acc[4][4] = {};
  for (int kt = 0; kt < DD; kt += 16) {
    #pragma unroll
    for (int i = 0; i < 4; ++i) {
      int e = tid + i * 256;
      As[e & 15][e >> 4] = A[(size_t)(row0 + (e >> 4)) * DD + kt + (e & 15)];
      Bs[e >> 6][e & 63] = Bm[(size_t)(kt + (e >> 6)) * NC + col0 + (e & 63)];
    }
    __syncthreads();
    #pragma unroll
    for (int kk = 0; kk < 16; ++kk) {
      float a[4], bv[4];
      #pragma unroll
      for (int i = 0; i < 4; ++i) a[i] = As[kk][ty * 4 + i];
      #pragma unroll
      for (int jj = 0; jj < 4; ++jj) bv[jj] = Bs[kk][tx * 4 + jj];
      #pragma unroll
      for (int i = 0; i < 4; ++i)
        #pragma unroll
        for (int jj = 0; jj < 4; ++jj)
          acc[i][jj] = fmaf(a[i], bv[jj], acc[i][jj]);
    }
    __syncthreads();
  }
  #pragma unroll
  for (int i = 0; i < 4; ++i)
    #pragma unroll
    for (int jj = 0; jj < 4; ++jj) {
      int c = col0 + tx * 4 + jj;
      int cc = PERM ? perm_col(c) : c;
      C[(size_t)(row0 + ty * 4 + i) * NC + cc] = acc[i][jj];
    }
}

// ---- scan: 256 WGs x 512 threads --------------------------------------------
__global__ __launch_bounds__(512, 1) void scan(
    const float* __restrict__ xpl,    // [NB*TP][NC] permuted cols
    const float* __restrict__ qv,     // [NB*TQ][NC] plain (this layer)
    const unsigned int* __restrict__ attk,  // [8][32][128] this layer
    const uint4* __restrict__ gatel,        // [8][32][128] this layer
    const float* __restrict__ wa,     // [256]
    const float* __restrict__ bias_f,
    const float* __restrict__ bias_iog,
    const float* __restrict__ mask_p,
    const float* __restrict__ mask_q,
    float* __restrict__ xch_p,        // [NB][NS][256] att partials
    float* __restrict__ xch_h,        // [NB][256]
    int* __restrict__ tag_h,          // [NB][NS] stride TAGSTR
    float* __restrict__ out,          // [NB*TP][256]
    int lbase)                        // layer*TPL
{
  const int bid = blockIdx.x;
  const int j = bid & 7, b = bid >> 3;
  const int tid = threadIdx.x;
  const int lane = tid & 63;

  __shared__ uint4 wg4[32][129];          // 66.0 KB gate weights
  __shared__ unsigned int watk[32][129];  // 16.5 KB att k-slice weights
  __shared__ unsigned int qT[TQL][129];   // 33.0 KB qWq bf16 pairs
  __shared__ unsigned int vl_l[GC][33];   // 16.9 KB Vl bf16 pairs
  __shared__ __align__(16) float h_lds[DD];
  __shared__ float hxa[DD];               // hw_att + x_att
  __shared__ float xg_s[GC];
  __shared__ float wa_s[DD];
  __shared__ float sc_part[4][66];
  __shared__ float al_s[TQL];
  __shared__ float pre_s[GC], bias_s[GC];

  const float* qv_b = qv + (size_t)b * TQL * NC;
  float* xch_p_b = xch_p + b * (NS * DD);
  float* xch_h_b = xch_h + b * DD;
  int* tags_b = tag_h + b * NS * TAGSTR;

  // ---- one-time preload
  {
    const uint4* gp = gatel + (size_t)j * 32 * GC;
    for (int i = tid; i < 32 * GC; i += 512) wg4[i >> 7][i & 127] = gp[i];
    const unsigned int* ap = attk + (size_t)j * 32 * 128;
    for (int i = tid; i < 32 * 128; i += 512) watk[i >> 7][i & 127] = ap[i];
    for (int i = tid; i < TQL * 128; i += 512) {
      int tq = i >> 7, aw = i & 127;
      qT[tq][aw] = packbf(qv_b[(size_t)tq * NC + 2 * aw],
                          qv_b[(size_t)tq * NC + 2 * aw + 1]);
    }
    for (int i = tid; i < GC * 32; i += 512) {
      int col = i >> 5, tw = i & 31;
      int g = col >> 5, m = (j << 5) + (col & 31);
      float v0 = qv_b[(size_t)(2 * tw) * NC + DD + (g << 8) + m];
      float v1 = qv_b[(size_t)(2 * tw + 1) * NC + DD + (g << 8) + m];
      vl_l[col][tw] = packbf(v0, v1);
    }
    for (int i = tid; i < DD; i += 512) wa_s[i] = wa[i];
    if (tid < GC) {
      int g = tid >> 5, m = (j << 5) + (tid & 31);
      bias_s[tid] = (g == 0) ? bias_f[m] : bias_iog[((g - 1) << 8) + m];
    }
  }
  float mq = mask_q[b * TQL + lane];    // softmax mask (wave 0, lane = tq)
  float cv = 0.f;                       // cell state, wave0 lanes<32
  __syncthreads();

  const int gcol = tid >> 1, ghalf = tid & 1;   // threads 0..255 roles

  for (int t = 0; t < TPL; ++t) {
    const float* xrow = xpl + ((size_t)b * TPL + t) * NC;
    // prefetch x (att part: tid<256; gate part: tid 256..383)
    float xv = 0.f;
    if (tid < DD) xv = xrow[tid];
    else if (tid < DD + GC) xv = xrow[DD + j * GC + (tid - DD)];
    float mtv = (tid < 64) ? mask_p[b * TPL + t] : 0.f;

    // ---- wait for h[t]+partials (wave 7 lanes poll; wave0 still publishing)
    if (t > 0 && tid >= 448 && tid < 448 + NS)
      spin_ge(&tags_b[(tid - 448) * TAGSTR], lbase + t);
    __syncthreads();                   // B0: tags seen; prev-step LDS uses done

    // ---- gather: h + 8 partials + x -> h_lds, hxa, xg_s
    if (tid < DD) {
      if (t > 0) {
        const float* pp = xch_p_b + tid;
        float s0 = aloadf(pp);
        float s1 = aloadf(pp + DD);
        float s2 = aloadf(pp + 2 * DD);
        float s3 = aloadf(pp + 3 * DD);
        float s4 = aloadf(pp + 4 * DD);
        float s5 = aloadf(pp + 5 * DD);
        float s6 = aloadf(pp + 6 * DD);
        float s7 = aloadf(pp + 7 * DD);
        float hv = aloadf(xch_h_b + tid);
        h_lds[tid] = hv;
        hxa[tid] = xv + ((s0 + s1) + (s2 + s3)) + ((s4 + s5) + (s6 + s7));
      } else {
        h_lds[tid] = 0.f;
        hxa[tid] = xv;
      }
    } else if (tid < DD + GC) {
      xg_s[tid - DD] = xv;
    }
    __syncthreads();                   // B1: h_lds, hxa, xg_s ready

    // ---- parallel: gate GEMV (threads 0..255) || scores (threads 256..511)
    float hwg = 0.f;
    if (tid < DD) {
      #pragma unroll
      for (int i = 0; i < 16; ++i) {
        int kq4 = 2 * i + ghalf;                 // interleaved k-split
        uint4 w = wg4[kq4][gcol];
        float4 h0 = *(const float4*)&h_lds[kq4 * 8];
        float4 h1 = *(const float4*)&h_lds[kq4 * 8 + 4];
        hwg = fmaf(h0.x, bflo(w.x), hwg); hwg = fmaf(h0.y, bfhi(w.x), hwg);
        hwg = fmaf(h0.z, bflo(w.y), hwg); hwg = fmaf(h0.w, bfhi(w.y), hwg);
        hwg = fmaf(h1.x, bflo(w.z), hwg); hwg = fmaf(h1.y, bfhi(w.z), hwg);
        hwg = fmaf(h1.z, bflo(w.w), hwg); hwg = fmaf(h1.w, bfhi(w.w), hwg);
      }
      hwg += __shfl_xor(hwg, 1);       // both partners hold full hw_gate[gcol]
    } else {
      int wv = (tid >> 6) - 4;         // 0..3 -> a-range [64wv, 64wv+64)
      int tq = lane;
      float p = 0.f;
      #pragma unroll
      for (int i = 0; i < 32; ++i) {
        int aw = wv * 32 + i;
        unsigned int q2 = qT[tq][aw];
        int a0 = 2 * aw, a1 = 2 * aw + 1;
        p = fmaf(fast_tanh(bflo(q2) + hxa[a0]), wa_s[a0], p);
        p = fmaf(fast_tanh(bfhi(q2) + hxa[a1]), wa_s[a1], p);
      }
      sc_part[wv][tq] = p;
    }
    __syncthreads();                   // B2: sc_part ready

    // ---- softmax (wave 0)
    if (tid < 64) {
      float v = (sc_part[0][tid] + sc_part[1][tid]) +
                (sc_part[2][tid] + sc_part[3][tid]);
      v = (mq > 0.f) ? v : -1e9f;
      float m = v;
      #pragma unroll
      for (int off = 32; off > 0; off >>= 1) m = fmaxf(m, __shfl_xor(m, off));
      float p = __expf(v - m);
      float su = p;
      #pragma unroll
      for (int off = 32; off > 0; off >>= 1) su += __shfl_xor(su, off);
      al_s[tid] = p * __builtin_amdgcn_rcpf(su);
    }
    __syncthreads();                   // B3: al_s ready

    // ---- pre: threads 0..255 (hold hwg): alpha@Vl 2-way tq split
    if (tid < DD) {
      float d0 = 0.f, d1 = 0.f;
      #pragma unroll
      for (int i = 0; i < 16; ++i) {
        int tw = ghalf * 16 + i;
        unsigned int v = vl_l[gcol][tw];
        d0 = fmaf(al_s[2 * tw], bflo(v), d0);
        d1 = fmaf(al_s[2 * tw + 1], bfhi(v), d1);
      }
      float dd = d0 + d1;
      dd += __shfl_xor(dd, 1);
      if (ghalf == 0)
        pre_s[gcol] = hwg + dd + xg_s[gcol] + bias_s[gcol];
    }
    __syncthreads();                   // B4: pre ready

    // ---- wave 0: gates -> h1 -> att-partial GEMV -> publish (one release)
    if (tid < 64) {
      float h1v = 0.f;
      if (tid < 32) {
        float f  = pre_s[tid];
        float ii = pre_s[32 + tid];
        float oo = pre_s[64 + tid];
        float g  = pre_s[96 + tid];
        int m = (j << 5) + tid;
        float c0 = cv, h0 = h_lds[m];
        float c1 = fast_sigmoid(f) * c0 + fast_sigmoid(ii) * fast_tanh(g);
        c1 = c1 * mtv + c0 * (1.f - mtv);
        h1v = fast_sigmoid(oo) * fast_tanh(c1);
        h1v = h1v * mtv + h0 * (1.f - mtv);
        cv = c1;
      }
      // partial[a] = sum_k h1[k] * Wr[32j+k][a], a = lane + 64*i
      float p0 = 0.f, p1 = 0.f, p2 = 0.f, p3 = 0.f;
      int awb = lane >> 1, sel = lane & 1;
      #pragma unroll
      for (int k = 0; k < 32; ++k) {
        float hk = __shfl(h1v, k);
        unsigned int w0 = watk[k][awb];
        unsigned int w1 = watk[k][awb + 32];
        unsigned int w2 = watk[k][awb + 64];
        unsigned int w3 = watk[k][awb + 96];
        p0 = fmaf(hk, sel ? bfhi(w0) : bflo(w0), p0);
        p1 = fmaf(hk, sel ? bfhi(w1) : bflo(w1), p1);
        p2 = fmaf(hk, sel ? bfhi(w2) : bflo(w2), p2);
        p3 = fmaf(hk, sel ? bfhi(w3) : bflo(w3), p3);
      }
      float* pb = xch_p_b + (j << 8);
      astoref(pb + lane,       p0);
      astoref(pb + lane + 64,  p1);
      astoref(pb + lane + 128, p2);
      astoref(pb + lane + 192, p3);
      if (tid < 32) {
        int m = (j << 5) + tid;
        astoref(xch_h_b + m, h1v);
        out[((size_t)b * TPL + t) * DD + m] = h1v;
      }
      if (tid == 0) radd(&tags_b[j * TAGSTR]);   // release drains wave-0 stores
    }
    // no trailing barrier: next iteration's B0 orders LDS reuse
  }
}

// -----------------------------------------------------------------------------
extern "C" void kernel_launch(void* const* d_in, const int* in_sizes, int n_in,
                              void* d_out, int out_size, void* d_ws, size_t ws_size,
                              hipStream_t stream) {
  const float* input_p  = (const float*)d_in[0];
  const float* mask_p   = (const float*)d_in[1];
  const float* input_q  = (const float*)d_in[2];
  const float* mask_q   = (const float*)d_in[3];
  const float* W_att_p  = (const float*)d_in[4];
  const float* W_att_q  = (const float*)d_in[5];
  const float* W_att_r  = (const float*)d_in[6];
  const float* w_att    = (const float*)d_in[7];
  const float* W_lstm   = (const float*)d_in[8];
  const float* bias_f   = (const float*)d_in[9];
  const float* bias_iog = (const float*)d_in[10];
  float* out = (float*)d_out;
  float* ws  = (float*)d_ws;
  (void)ws_size; (void)in_sizes; (void)n_in; (void)out_size;

  const size_t SZ_XPL  = (size_t)NB * TPL * NC;
  const size_t SZ_QV   = (size_t)NB * TQL * NC;
  const size_t SZ_W    = (size_t)DD * NC;
  const size_t SZ_ATTK = (size_t)NS * 32 * 128;   // uint per layer
  const size_t SZ_GATL = (size_t)NS * 32 * GC;    // uint4 per layer

  float* ws_xpl = ws;
  float* ws_qv  = ws_xpl + SZ_XPL;
  float* ws_wx  = ws_qv  + 2 * SZ_QV;
  float* ws_wqv = ws_wx  + 2 * SZ_W;
  float* ws_o0  = ws_wqv + 2 * SZ_W;
  unsigned int* ws_attk = (unsigned int*)(ws_o0 + (size_t)NB * TPL * DD);
  uint4* ws_gatl = (uint4*)(ws_attk + 2 * SZ_ATTK);
  float* ws_xp   = (float*)(ws_gatl + 2 * SZ_GATL);  // xch_p [NB][8][256]
  float* ws_xh   = ws_xp + NB * NS * DD;             // xch_h [NB][256]
  int*   ws_tag  = (int*)(ws_xh + NB * DD);          // tag_h [NB][NS] x TAGSTR

  dim3 gpack((DD * NC + 255) / 256, 2);
  pack_weights<<<gpack, 256, 0, stream>>>(W_att_p, W_att_q, W_lstm, ws_wx, ws_wqv);
  pack_attk<<<(2 * NS * 32 * 128 + 255) / 256, 256, 0, stream>>>(W_att_r, ws_attk);
  pack_gatel<<<(2 * NS * 32 * GC + 255) / 256, 256, 0, stream>>>(W_lstm, ws_gatl);
  hipMemsetAsync(ws_tag, 0, NB * NS * TAGSTR * sizeof(int), stream);

  for (int d = 0; d < 2; ++d) {
    dim3 g(NC / 64, (NB * TQL) / 64);
    sgemm<false><<<g, 256, 0, stream>>>(input_q, ws_wqv + d * SZ_W, ws_qv + d * SZ_QV);
  }

  // layer 0
  {
    dim3 g(NC / 64, (NB * TPL) / 64);
    sgemm<true><<<g, 256, 0, stream>>>(input_p, ws_wx, ws_xpl);
    scan<<<NB * NS, 512, 0, stream>>>(ws_xpl, ws_qv, ws_attk, ws_gatl,
                                      w_att, bias_f, bias_iog, mask_p, mask_q,
                                      ws_xp, ws_xh, ws_tag, ws_o0, 0);
  }
  // layer 1
  {
    dim3 g(NC / 64, (NB * TPL) / 64);
    sgemm<true><<<g, 256, 0, stream>>>(ws_o0, ws_wx + SZ_W, ws_xpl);
    scan<<<NB * NS, 512, 0, stream>>>(ws_xpl, ws_qv + SZ_QV, ws_attk + SZ_ATTK,
                                      ws_gatl + SZ_GATL, w_att + DD, bias_f + DD,
                                      bias_iog + 3 * DD, mask_p, mask_q,
                                      ws_xp, ws_xh, ws_tag, out, TPL);
  }
}

// Round 13
// 8223.923 us; speedup vs baseline: 1.2184x; 1.2184x over previous
//
#include <hip/hip_runtime.h>
#include <hip/hip_bf16.h>

// StackedMatchLSTM on MI355X — r7 structure (proven 4.0ms scans) +
// consumption-ordered LDS layouts (zero bank conflicts by construction).
// B=32, TP=512, TQ=64, DP=DQ=H=AH=256, NL=2.
// Scan: 256 WGs (8 slices x 32 batches) x 512 threads. Slice j owns 32 att
// cols + 128 gate cols; weights LDS-resident (bf16). Per step: poll h ->
// att GEMV -> scores -> publish score partial -> gate GEMV (hides score
// flight) -> poll scores -> softmax -> pre -> gates -> publish h.
// Sync: relaxed agent payload stores + per-slice RMW tag (release-add /
// relaxed add-0 spin), wave-0-only publish — the r5-r9-proven primitive.
// All LDS weight tables stored [iter][tid] so each wave reads contiguous
// 512B per instruction (r7 had 4.03e8 bank-conflict cycles from k-split
// row aliasing; gate k-split interleaved kq=i*4+gq for distinct h banks).

#define NB 32
#define TPL 512
#define TQL 64
#define DD 256      // DP = DQ = H = AH
#define H4 1024     // 4*H
#define NC 1280     // AH + 4H
#define NS 8        // slices per batch
#define SC 160      // xpl cols per slice = 32 att + 128 gate
#define GC 128      // gate cols per slice
#define TAGSTR 16   // ints between tags (64 B)

__device__ __forceinline__ float fast_tanh(float x) {
  float xc = fminf(fmaxf(x, -9.f), 9.f);
  float e = __expf(2.f * xc);
  return (e - 1.f) * __builtin_amdgcn_rcpf(e + 1.f);
}
__device__ __forceinline__ float fast_sigmoid(float x) {
  return __builtin_amdgcn_rcpf(1.f + __expf(-x));
}
__device__ __forceinline__ float bflo(unsigned int w) { return __uint_as_float(w << 16); }
__device__ __forceinline__ float bfhi(unsigned int w) { return __uint_as_float(w & 0xffff0000u); }
__device__ __forceinline__ unsigned int packbf(float a, float b) {
  unsigned int lo = __hip_bfloat16_raw(__float2bfloat16(a)).x;
  unsigned int hi = __hip_bfloat16_raw(__float2bfloat16(b)).x;
  return lo | (hi << 16);
}

// ---- agent-scope sync: RMW-only (executes at LLC, stale-proof) --------------
__device__ __forceinline__ float aloadf(const float* p) {
  return __hip_atomic_load(p, __ATOMIC_RELAXED, __HIP_MEMORY_SCOPE_AGENT);
}
__device__ __forceinline__ void astoref(float* p, float v) {
  __hip_atomic_store(p, v, __ATOMIC_RELAXED, __HIP_MEMORY_SCOPE_AGENT);
}
__device__ __forceinline__ void radd(int* p) {
  __hip_atomic_fetch_add(p, 1, __ATOMIC_RELEASE, __HIP_MEMORY_SCOPE_AGENT);
}
__device__ __forceinline__ void spin_ge(int* p, int tgt) {
  int guard = 0;
  while (__hip_atomic_fetch_add(p, 0, __ATOMIC_RELAXED, __HIP_MEMORY_SCOPE_AGENT) < tgt) {
    __builtin_amdgcn_s_sleep(1);
    if (++guard > (1 << 26)) break;   // bail instead of hanging the harness
  }
}

// permuted xpl cols: slice-major blocks of 160: 32 att | f|i|o|g x32
__device__ __forceinline__ int perm_col(int c) {
  if (c < DD) return (c >> 5) * SC + (c & 31);
  int cc = c - DD;
  int g = cc >> 8;          // 0..3 = f,i,o,g
  int m = cc & 255;         // h-elem
  return (m >> 5) * SC + 32 + (g << 5) + (m & 31);
}

// ---- weight prep ------------------------------------------------------------
__global__ __launch_bounds__(256) void pack_weights(
    const float* __restrict__ Wp, const float* __restrict__ Wq,
    const float* __restrict__ Wl,
    float* __restrict__ wx, float* __restrict__ wqv)
{
  int d = blockIdx.y;
  int idx = blockIdx.x * 256 + threadIdx.x;
  if (idx >= DD * NC) return;
  int k = idx / NC, j = idx % NC;
  int o = d * DD * NC + idx;
  const float* Wld = Wl + (size_t)d * 768 * H4;
  if (j < DD) {
    int s = d * DD * DD + k * DD + j;
    wx[o] = Wp[s]; wqv[o] = Wq[s];
  } else {
    int c = j - DD;
    wx[o]  = Wld[(size_t)k * H4 + c];
    wqv[o] = Wld[(size_t)(DD + k) * H4 + c];
  }
}

// attl, consumption order: [(d*8+j)][i(4)][slot(512)], slot = ak*32 + acol.
// uint2 = k's {4kq..4kq+3} of col (32j+acol), kq = ak*4 + i.
__global__ __launch_bounds__(256) void pack_attl(
    const float* __restrict__ Wr, uint2* __restrict__ attl)
{
  int idx = blockIdx.x * 256 + threadIdx.x;       // 2*8*4*512 = 32768
  if (idx >= 2 * NS * 4 * 512) return;
  int slot = idx & 511; int r = idx >> 9;
  int i = r & 3; r >>= 2;
  int j = r & 7; int d = r >> 3;
  int acol = slot & 31, ak = slot >> 5;
  int kq = ak * 4 + i;
  int col = (j << 5) + acol;
  float v[4];
  #pragma unroll
  for (int kr = 0; kr < 4; ++kr)
    v[kr] = Wr[((size_t)d * DD + kq * 4 + kr) * DD + col];
  attl[idx] = make_uint2(packbf(v[0], v[1]), packbf(v[2], v[3]));
}

// gatel, consumption order: [(d*8+j)][i(16)][slot(512)], slot: gcol=slot>>2,
// gq=slot&3. uint2 = k's {4kq..4kq+3} of gate col gcol, kq = i*4 + gq
// (interleaved so 4 gq's hit distinct h_lds bank quads).
__global__ __launch_bounds__(256) void pack_gatel(
    const float* __restrict__ Wl, uint2* __restrict__ gatel)
{
  int idx = blockIdx.x * 256 + threadIdx.x;       // 2*8*16*512 = 131072
  if (idx >= 2 * NS * 16 * 512) return;
  int slot = idx & 511; int r = idx >> 9;
  int i = r & 15; r >>= 4;
  int j = r & 7; int d = r >> 3;
  int gcol = slot >> 2, gq = slot & 3;
  int kq = i * 4 + gq;
  int g = gcol >> 5, pos = gcol & 31;
  float v[4];
  #pragma unroll
  for (int kr = 0; kr < 4; ++kr) {
    int k = kq * 4 + kr;
    v[kr] = Wl[((size_t)d * 768 + 512 + k) * H4 + (g << 8) + (j << 5) + pos];
  }
  gatel[idx] = make_uint2(packbf(v[0], v[1]), packbf(v[2], v[3]));
}

// ---- C[M][1280] = A[M][256] @ B[256][1280], fp32 ----------------------------
template <bool PERM>
__global__ __launch_bounds__(256) void sgemm(
    const float* __restrict__ A, const float* __restrict__ Bm,
    float* __restrict__ C)
{
  __shared__ float As[16][65];
  __shared__ float Bs[16][64];
  int tid = threadIdx.x;
  int tx = tid & 15, ty = tid >> 4;
  int col0 = blockIdx.x * 64, row0 = blockIdx.y * 64;
  float acc[4][4] = {};
  for (int kt = 0; kt < DD; kt += 16) {
    #pragma unroll
    for (int i = 0; i < 4; ++i) {
      int e = tid + i * 256;
      As[e & 15][e >> 4] = A[(size_t)(row0 + (e >> 4)) * DD + kt + (e & 15)];
      Bs[e >> 6][e & 63] = Bm[(size_t)(kt + (e >> 6)) * NC + col0 + (e & 63)];
    }
    __syncthreads();
    #pragma unroll
    for (int kk = 0; kk < 16; ++kk) {
      float a[4], bv[4];
      #pragma unroll
      for (int i = 0; i < 4; ++i) a[i] = As[kk][ty * 4 + i];
      #pragma unroll
      for (int jj = 0; jj < 4; ++jj) bv[jj] = Bs[kk][tx * 4 + jj];
      #pragma unroll
      for (int i = 0; i < 4; ++i)
        #pragma unroll
        for (int jj = 0; jj < 4; ++jj)
          acc[i][jj] = fmaf(a[i], bv[jj], acc[i][jj]);
    }
    __syncthreads();
  }
  #pragma unroll
  for (int i = 0; i < 4; ++i)
    #pragma unroll
    for (int jj = 0; jj < 4; ++jj) {
      int c = col0 + tx * 4 + jj;
      int cc = PERM ? perm_col(c) : c;
      C[(size_t)(row0 + ty * 4 + i) * NC + cc] = acc[i][jj];
    }
}

// ---- scan: 256 WGs x 512 threads, weights LDS-resident ----------------------
__global__ __launch_bounds__(512, 1) void scan(
    const float* __restrict__ xpl,    // [NB*TP][NC] permuted cols
    const float* __restrict__ qv,     // [NB*TQ][NC] plain (this layer)
    const uint2* __restrict__ attl,   // this layer's [8][4][512]
    const uint2* __restrict__ gatel,  // this layer's [8][16][512]
    const float* __restrict__ wa,     // [256]
    const float* __restrict__ bias_f,
    const float* __restrict__ bias_iog,
    const float* __restrict__ mask_p,
    const float* __restrict__ mask_q,
    float* __restrict__ xch_s,        // [NB][NS][64]
    float* __restrict__ xch_h,        // [NB][256]
    int* __restrict__ tag_s,          // [NB][NS] stride TAGSTR
    int* __restrict__ tag_h,          // [NB][NS] stride TAGSTR
    float* __restrict__ out,          // [NB*TP][256]
    int lbase)                        // layer*TPL
{
  const int bid = blockIdx.x;
  const int j = bid & 7, b = bid >> 3;
  const int tid = threadIdx.x;
  const int lane = tid & 63;

  __shared__ uint2 wg_l[16][512];        // 64 KB gate weights, [iter][tid]
  __shared__ uint2 wat_l[4][512];        // 16 KB att weights, [iter][tid]
  __shared__ unsigned int vl_l[8][512];  // 16 KB Vl bf16 pairs, [iter][tid]
  __shared__ float qT[32][65];           //  8.3 KB qWq^T (own att cols)
  __shared__ __align__(16) float h_lds[DD];
  __shared__ float xsl[SC];
  __shared__ float hw_att[32], waa[32], c_sh[32];
  __shared__ float att_part[16][33];
  __shared__ float sc_part[8][TQL];
  __shared__ float al_s[TQL];
  __shared__ float pre_s[GC], bias_s[GC];

  const float* qv_b = qv + (size_t)b * TQL * NC;
  float* xch_s_b = xch_s + b * (NS * TQL);
  float* xch_h_b = xch_h + b * DD;
  int* tags_s = tag_s + b * NS * TAGSTR;
  int* tags_h = tag_h + b * NS * TAGSTR;

  // ---- one-time preload: weights + per-batch activations into LDS
  {
    const uint2* gp = gatel + (size_t)j * 16 * 512;
    for (int i = tid; i < 16 * 512; i += 512) wg_l[i >> 9][i & 511] = gp[i];
    const uint2* ap = attl + (size_t)j * 4 * 512;
    for (int i = tid; i < 4 * 512; i += 512) wat_l[i >> 9][i & 511] = ap[i];
    for (int i = tid; i < TQL * 32; i += 512) {
      int tq = i >> 5, a = i & 31;
      qT[a][tq] = qv_b[(size_t)tq * NC + (j << 5) + a];
    }
    // vl_l[ii][slot]: slot -> gcol=slot>>2, gq=slot&3; tw = gq*8+ii
    for (int f = tid; f < 8 * 512; f += 512) {
      int ii = f >> 9, slot = f & 511;
      int gcol = slot >> 2, gq = slot & 3;
      int tw = gq * 8 + ii;
      int g = gcol >> 5, m = (j << 5) + (gcol & 31);
      float v0 = qv_b[(size_t)(2 * tw) * NC + DD + (g << 8) + m];
      float v1 = qv_b[(size_t)(2 * tw + 1) * NC + DD + (g << 8) + m];
      vl_l[ii][slot] = packbf(v0, v1);
    }
    if (tid < 32) { waa[tid] = wa[(j << 5) + tid]; c_sh[tid] = 0.f; }
    if (tid < GC) {
      int g = tid >> 5, m = (j << 5) + (tid & 31);
      bias_s[tid] = (g == 0) ? bias_f[m] : bias_iog[((g - 1) << 8) + m];
    }
  }
  float mq = mask_q[b * TQL + lane];    // softmax mask, lane = tq (wave 0 uses)
  __syncthreads();

  // role indices
  const int ak = tid >> 5;                        // att: 16-way k-split
  const int stq = tid & 63, ssub = tid >> 6;      // scores: 8 subs x 4 cols
  const int gcol = tid >> 2, gq = tid & 3;        // gate/pre: 4-way k/tq split

  for (int t = 0; t < TPL; ++t) {
    const float* xrow = xpl + ((size_t)b * TPL + t) * NC + j * SC;
    float xv = (tid < SC) ? xrow[tid] : 0.f;      // in flight during poll

    // ---- wait for h[t]
    if (t > 0 && tid < NS) spin_ge(&tags_h[tid * TAGSTR], lbase + t);
    __syncthreads();                   // pollers done; prev-step LDS reads done
    if (tid < DD) h_lds[tid] = (t > 0) ? aloadf(xch_h_b + tid) : 0.f;
    if (tid < SC) xsl[tid] = xv;
    __syncthreads();                   // B1: h_lds, xsl ready

    // ---- att GEMV from LDS: 32 cols x 16-way k-split (16 k each)
    {
      float a0 = 0.f, a1 = 0.f;
      #pragma unroll
      for (int i = 0; i < 4; ++i) {
        int kq = ak * 4 + i;
        uint2 w = wat_l[i][tid];
        float4 h0 = *(const float4*)&h_lds[kq * 4];
        a0 = fmaf(h0.x, bflo(w.x), a0); a1 = fmaf(h0.y, bfhi(w.x), a1);
        a0 = fmaf(h0.z, bflo(w.y), a0); a1 = fmaf(h0.w, bfhi(w.y), a1);
      }
      att_part[ak][tid & 31] = a0 + a1;
    }
    __syncthreads();                   // B2
    if (tid < 32) {
      float s = 0.f;
      #pragma unroll
      for (int i = 0; i < 16; ++i) s += att_part[i][tid];
      hw_att[tid] = s;
    }
    __syncthreads();                   // B3: hw_att ready

    // ---- scores: 64 tq x 8 subs (4 a each)
    {
      float p = 0.f;
      #pragma unroll
      for (int i = 0; i < 4; ++i) {
        int a = ssub * 4 + i;
        p = fmaf(fast_tanh(qT[a][stq] + xsl[a] + hw_att[a]), waa[a], p);
      }
      sc_part[ssub][stq] = p;
    }
    __syncthreads();                   // B4
    // ---- publish score partial (wave 0), tag
    if (tid < TQL) {
      float s = 0.f;
      #pragma unroll
      for (int q = 0; q < 8; ++q) s += sc_part[q][tid];
      astoref(xch_s_b + (j << 6) + tid, s);
    }
    if (tid == 0) radd(&tags_s[j * TAGSTR]);

    // ---- gate GEMV from LDS (all 512): hides score flight
    float hwg;
    {
      float g0 = 0.f, g1 = 0.f;
      #pragma unroll
      for (int i = 0; i < 16; ++i) {
        int kq = i * 4 + gq;                     // interleaved k-split
        uint2 w = wg_l[i][tid];
        float4 h0 = *(const float4*)&h_lds[kq * 4];
        g0 = fmaf(h0.x, bflo(w.x), g0); g1 = fmaf(h0.y, bfhi(w.x), g1);
        g0 = fmaf(h0.z, bflo(w.y), g0); g1 = fmaf(h0.w, bfhi(w.y), g1);
      }
      hwg = g0 + g1;
      hwg += __shfl_xor(hwg, 1);
      hwg += __shfl_xor(hwg, 2);       // all 4 partners hold full hw_gate[gcol]
    }

    // ---- poll score tags, gather (1 load/thread), softmax
    if (tid < NS) spin_ge(&tags_s[tid * TAGSTR], lbase + t + 1);
    __syncthreads();                   // B5
    sc_part[tid >> 6][stq] = aloadf(xch_s_b + ((tid >> 6) << 6) + stq);
    __syncthreads();                   // B6
    if (tid < TQL) {
      float v = 0.f;
      #pragma unroll
      for (int q = 0; q < 8; ++q) v += sc_part[q][tid];
      v = (mq > 0.f) ? v : -1e9f;
      float m = v;
      #pragma unroll
      for (int off = 32; off > 0; off >>= 1) m = fmaxf(m, __shfl_xor(m, off));
      float p = __expf(v - m);
      float su = p;
      #pragma unroll
      for (int off = 32; off > 0; off >>= 1) su += __shfl_xor(su, off);
      al_s[tid] = p * __builtin_amdgcn_rcpf(su);
    }
    __syncthreads();                   // B7: al_s ready

    // ---- pre: alpha@Vl (4-way tq split) + hwg + x + bias
    {
      float d0 = 0.f, d1 = 0.f;
      #pragma unroll
      for (int i = 0; i < 8; ++i) {
        int tw = gq * 8 + i;
        unsigned int v = vl_l[i][tid];
        d0 = fmaf(al_s[2 * tw], bflo(v), d0);
        d1 = fmaf(al_s[2 * tw + 1], bfhi(v), d1);
      }
      float d = d0 + d1;
      d += __shfl_xor(d, 1);
      d += __shfl_xor(d, 2);
      if (gq == 0)
        pre_s[gcol] = hwg + d + xsl[32 + gcol] + bias_s[gcol];
    }
    __syncthreads();                   // B8: pre ready

    // ---- gates + state for own 32 h-elems; publish h slice + tag
    if (tid < 32) {
      float f  = pre_s[tid];
      float ii = pre_s[32 + tid];
      float oo = pre_s[64 + tid];
      float g  = pre_s[96 + tid];
      float mtv = mask_p[b * TPL + t];
      int m = (j << 5) + tid;
      float c0 = c_sh[tid], h0 = h_lds[m];
      float c1 = fast_sigmoid(f) * c0 + fast_sigmoid(ii) * fast_tanh(g);
      c1 = c1 * mtv + c0 * (1.f - mtv);
      float h1 = fast_sigmoid(oo) * fast_tanh(c1);
      h1 = h1 * mtv + h0 * (1.f - mtv);
      c_sh[tid] = c1;
      astoref(xch_h_b + m, h1);        // payload straight to LLC
      if (tid == 0) radd(&tags_h[j * TAGSTR]);   // release drains wave stores
      out[((size_t)b * TPL + t) * DD + m] = h1;
    }
    // no trailing barrier: next iteration's post-poll barrier orders h_lds reuse
  }
}

// -----------------------------------------------------------------------------
extern "C" void kernel_launch(void* const* d_in, const int* in_sizes, int n_in,
                              void* d_out, int out_size, void* d_ws, size_t ws_size,
                              hipStream_t stream) {
  const float* input_p  = (const float*)d_in[0];
  const float* mask_p   = (const float*)d_in[1];
  const float* input_q  = (const float*)d_in[2];
  const float* mask_q   = (const float*)d_in[3];
  const float* W_att_p  = (const float*)d_in[4];
  const float* W_att_q  = (const float*)d_in[5];
  const float* W_att_r  = (const float*)d_in[6];
  const float* w_att    = (const float*)d_in[7];
  const float* W_lstm   = (const float*)d_in[8];
  const float* bias_f   = (const float*)d_in[9];
  const float* bias_iog = (const float*)d_in[10];
  float* out = (float*)d_out;
  float* ws  = (float*)d_ws;
  (void)ws_size; (void)in_sizes; (void)n_in; (void)out_size;

  const size_t SZ_XPL  = (size_t)NB * TPL * NC;
  const size_t SZ_QV   = (size_t)NB * TQL * NC;
  const size_t SZ_W    = (size_t)DD * NC;
  const size_t SZ_ATTL = (size_t)NS * 4 * 512;    // uint2 per layer
  const size_t SZ_GATL = (size_t)NS * 16 * 512;   // uint2 per layer

  float* ws_xpl = ws;
  float* ws_qv  = ws_xpl + SZ_XPL;
  float* ws_wx  = ws_qv  + 2 * SZ_QV;
  float* ws_wqv = ws_wx  + 2 * SZ_W;
  float* ws_o0  = ws_wqv + 2 * SZ_W;
  uint2* ws_attl = (uint2*)(ws_o0 + (size_t)NB * TPL * DD);
  uint2* ws_gatl = ws_attl + 2 * SZ_ATTL;
  float* ws_xs   = (float*)(ws_gatl + 2 * SZ_GATL);  // xch_s [NB][8][64]
  float* ws_xh   = ws_xs + NB * NS * TQL;            // xch_h [NB][256]
  int*   ws_tag  = (int*)(ws_xh + NB * DD);
  int*   tag_s   = ws_tag;                           // [NB][NS] x TAGSTR
  int*   tag_h   = ws_tag + NB * NS * TAGSTR;

  dim3 gpack((DD * NC + 255) / 256, 2);
  pack_weights<<<gpack, 256, 0, stream>>>(W_att_p, W_att_q, W_lstm, ws_wx, ws_wqv);
  pack_attl<<<(2 * NS * 4 * 512 + 255) / 256, 256, 0, stream>>>(W_att_r, ws_attl);
  pack_gatel<<<(2 * NS * 16 * 512 + 255) / 256, 256, 0, stream>>>(W_lstm, ws_gatl);
  hipMemsetAsync(ws_tag, 0, 2 * NB * NS * TAGSTR * sizeof(int), stream);

  for (int d = 0; d < 2; ++d) {
    dim3 g(NC / 64, (NB * TQL) / 64);
    sgemm<false><<<g, 256, 0, stream>>>(input_q, ws_wqv + d * SZ_W, ws_qv + d * SZ_QV);
  }

  // layer 0
  {
    dim3 g(NC / 64, (NB * TPL) / 64);
    sgemm<true><<<g, 256, 0, stream>>>(input_p, ws_wx, ws_xpl);
    scan<<<NB * NS, 512, 0, stream>>>(ws_xpl, ws_qv, ws_attl, ws_gatl,
                                      w_att, bias_f, bias_iog, mask_p, mask_q,
                                      ws_xs, ws_xh, tag_s, tag_h, ws_o0, 0);
  }
  // layer 1
  {
    dim3 g(NC / 64, (NB * TPL) / 64);
    sgemm<true><<<g, 256, 0, stream>>>(ws_o0, ws_wx + SZ_W, ws_xpl);
    scan<<<NB * NS, 512, 0, stream>>>(ws_xpl, ws_qv + SZ_QV, ws_attl + SZ_ATTL,
                                      ws_gatl + SZ_GATL, w_att + DD, bias_f + DD,
                                      bias_iog + 3 * DD, mask_p, mask_q,
                                      ws_xs, ws_xh, tag_s, tag_h, out, TPL);
  }
}

// Round 14
// 4021.051 us; speedup vs baseline: 2.4919x; 2.0452x over previous
//
#include <hip/hip_runtime.h>
#include <hip/hip_bf16.h>

// StackedMatchLSTM on MI355X — r13 structure (proven, 0 bank conflicts) with
// seq-stamped 64-bit payload exchange (1 LLC round trip per exchange).
// B=32, TP=512, TQ=64, DP=DQ=H=AH=256, NL=2.
// Scan: 256 WGs (8 slices x 32 batches) x 512 threads. Slice j owns 32 att
// cols + 128 gate cols; weights LDS-resident (bf16, consumption-ordered
// [iter][tid] layouts -> zero bank conflicts). Per step: spin-load h ->
// att GEMV -> scores -> publish scores -> gate GEMV (hides score flight) ->
// spin-load scores -> softmax -> pre -> gates -> publish h.
// Exchange: each float published as (bits, seq) in one relaxed agent-scope
// 8B atomic; consumers spin on their own element until seq matches. No tags,
// no release ordering needed — every element self-validates.

#define NB 32
#define TPL 512
#define TQL 64
#define DD 256      // DP = DQ = H = AH
#define H4 1024     // 4*H
#define NC 1280     // AH + 4H
#define NS 8        // slices per batch
#define SC 160      // xpl cols per slice = 32 att + 128 gate
#define GC 128      // gate cols per slice

typedef unsigned long long u64;

__device__ __forceinline__ float fast_tanh(float x) {
  float xc = fminf(fmaxf(x, -9.f), 9.f);
  float e = __expf(2.f * xc);
  return (e - 1.f) * __builtin_amdgcn_rcpf(e + 1.f);
}
__device__ __forceinline__ float fast_sigmoid(float x) {
  return __builtin_amdgcn_rcpf(1.f + __expf(-x));
}
__device__ __forceinline__ float bflo(unsigned int w) { return __uint_as_float(w << 16); }
__device__ __forceinline__ float bfhi(unsigned int w) { return __uint_as_float(w & 0xffff0000u); }
__device__ __forceinline__ unsigned int packbf(float a, float b) {
  unsigned int lo = __hip_bfloat16_raw(__float2bfloat16(a)).x;
  unsigned int hi = __hip_bfloat16_raw(__float2bfloat16(b)).x;
  return lo | (hi << 16);
}

// ---- seq-stamped payload exchange (relaxed agent atomics, LLC-coherent) -----
__device__ __forceinline__ u64 aload64(const u64* p) {
  return __hip_atomic_load(p, __ATOMIC_RELAXED, __HIP_MEMORY_SCOPE_AGENT);
}
__device__ __forceinline__ void astore64(u64* p, u64 v) {
  __hip_atomic_store(p, v, __ATOMIC_RELAXED, __HIP_MEMORY_SCOPE_AGENT);
}
__device__ __forceinline__ u64 packsv(float val, unsigned int seq) {
  return ((u64)seq << 32) | (u64)__float_as_uint(val);
}
__device__ __forceinline__ float spinload(const u64* p, unsigned int seq) {
  u64 v = aload64(p);
  int guard = 0;
  while ((unsigned int)(v >> 32) != seq) {
    __builtin_amdgcn_s_sleep(1);
    v = aload64(p);
    if (++guard > (1 << 24)) break;   // bail instead of hanging the harness
  }
  return __uint_as_float((unsigned int)v);
}

// permuted xpl cols: slice-major blocks of 160: 32 att | f|i|o|g x32
__device__ __forceinline__ int perm_col(int c) {
  if (c < DD) return (c >> 5) * SC + (c & 31);
  int cc = c - DD;
  int g = cc >> 8;          // 0..3 = f,i,o,g
  int m = cc & 255;         // h-elem
  return (m >> 5) * SC + 32 + (g << 5) + (m & 31);
}

// ---- weight prep ------------------------------------------------------------
__global__ __launch_bounds__(256) void pack_weights(
    const float* __restrict__ Wp, const float* __restrict__ Wq,
    const float* __restrict__ Wl,
    float* __restrict__ wx, float* __restrict__ wqv)
{
  int d = blockIdx.y;
  int idx = blockIdx.x * 256 + threadIdx.x;
  if (idx >= DD * NC) return;
  int k = idx / NC, j = idx % NC;
  int o = d * DD * NC + idx;
  const float* Wld = Wl + (size_t)d * 768 * H4;
  if (j < DD) {
    int s = d * DD * DD + k * DD + j;
    wx[o] = Wp[s]; wqv[o] = Wq[s];
  } else {
    int c = j - DD;
    wx[o]  = Wld[(size_t)k * H4 + c];
    wqv[o] = Wld[(size_t)(DD + k) * H4 + c];
  }
}

// attl, consumption order: [(d*8+j)][i(4)][slot(512)], slot = ak*32 + acol.
// uint2 = k's {4kq..4kq+3} of col (32j+acol), kq = ak*4 + i.
__global__ __launch_bounds__(256) void pack_attl(
    const float* __restrict__ Wr, uint2* __restrict__ attl)
{
  int idx = blockIdx.x * 256 + threadIdx.x;       // 2*8*4*512 = 32768
  if (idx >= 2 * NS * 4 * 512) return;
  int slot = idx & 511; int r = idx >> 9;
  int i = r & 3; r >>= 2;
  int j = r & 7; int d = r >> 3;
  int acol = slot & 31, ak = slot >> 5;
  int kq = ak * 4 + i;
  int col = (j << 5) + acol;
  float v[4];
  #pragma unroll
  for (int kr = 0; kr < 4; ++kr)
    v[kr] = Wr[((size_t)d * DD + kq * 4 + kr) * DD + col];
  attl[idx] = make_uint2(packbf(v[0], v[1]), packbf(v[2], v[3]));
}

// gatel, consumption order: [(d*8+j)][i(16)][slot(512)], slot: gcol=slot>>2,
// gq=slot&3. uint2 = k's {4kq..4kq+3} of gate col gcol, kq = i*4 + gq.
__global__ __launch_bounds__(256) void pack_gatel(
    const float* __restrict__ Wl, uint2* __restrict__ gatel)
{
  int idx = blockIdx.x * 256 + threadIdx.x;       // 2*8*16*512 = 131072
  if (idx >= 2 * NS * 16 * 512) return;
  int slot = idx & 511; int r = idx >> 9;
  int i = r & 15; r >>= 4;
  int j = r & 7; int d = r >> 3;
  int gcol = slot >> 2, gq = slot & 3;
  int kq = i * 4 + gq;
  int g = gcol >> 5, pos = gcol & 31;
  float v[4];
  #pragma unroll
  for (int kr = 0; kr < 4; ++kr) {
    int k = kq * 4 + kr;
    v[kr] = Wl[((size_t)d * 768 + 512 + k) * H4 + (g << 8) + (j << 5) + pos];
  }
  gatel[idx] = make_uint2(packbf(v[0], v[1]), packbf(v[2], v[3]));
}

// ---- C[M][1280] = A[M][256] @ B[256][1280], fp32 ----------------------------
template <bool PERM>
__global__ __launch_bounds__(256) void sgemm(
    const float* __restrict__ A, const float* __restrict__ Bm,
    float* __restrict__ C)
{
  __shared__ float As[16][65];
  __shared__ float Bs[16][64];
  int tid = threadIdx.x;
  int tx = tid & 15, ty = tid >> 4;
  int col0 = blockIdx.x * 64, row0 = blockIdx.y * 64;
  float acc[4][4] = {};
  for (int kt = 0; kt < DD; kt += 16) {
    #pragma unroll
    for (int i = 0; i < 4; ++i) {
      int e = tid + i * 256;
      As[e & 15][e >> 4] = A[(size_t)(row0 + (e >> 4)) * DD + kt + (e & 15)];
      Bs[e >> 6][e & 63] = Bm[(size_t)(kt + (e >> 6)) * NC + col0 + (e & 63)];
    }
    __syncthreads();
    #pragma unroll
    for (int kk = 0; kk < 16; ++kk) {
      float a[4], bv[4];
      #pragma unroll
      for (int i = 0; i < 4; ++i) a[i] = As[kk][ty * 4 + i];
      #pragma unroll
      for (int jj = 0; jj < 4; ++jj) bv[jj] = Bs[kk][tx * 4 + jj];
      #pragma unroll
      for (int i = 0; i < 4; ++i)
        #pragma unroll
        for (int jj = 0; jj < 4; ++jj)
          acc[i][jj] = fmaf(a[i], bv[jj], acc[i][jj]);
    }
    __syncthreads();
  }
  #pragma unroll
  for (int i = 0; i < 4; ++i)
    #pragma unroll
    for (int jj = 0; jj < 4; ++jj) {
      int c = col0 + tx * 4 + jj;
      int cc = PERM ? perm_col(c) : c;
      C[(size_t)(row0 + ty * 4 + i) * NC + cc] = acc[i][jj];
    }
}

// ---- scan: 256 WGs x 512 threads, weights LDS-resident ----------------------
__global__ __launch_bounds__(512, 1) void scan(
    const float* __restrict__ xpl,    // [NB*TP][NC] permuted cols
    const float* __restrict__ qv,     // [NB*TQ][NC] plain (this layer)
    const uint2* __restrict__ attl,   // this layer's [8][4][512]
    const uint2* __restrict__ gatel,  // this layer's [8][16][512]
    const float* __restrict__ wa,     // [256]
    const float* __restrict__ bias_f,
    const float* __restrict__ bias_iog,
    const float* __restrict__ mask_p,
    const float* __restrict__ mask_q,
    u64* __restrict__ xch_s,          // [NB][NS][64] seq-stamped scores
    u64* __restrict__ xch_h,          // [NB][256]  seq-stamped h
    float* __restrict__ out,          // [NB*TP][256]
    int lbase)                        // layer*TPL
{
  const int bid = blockIdx.x;
  const int j = bid & 7, b = bid >> 3;
  const int tid = threadIdx.x;
  const int lane = tid & 63;

  __shared__ uint2 wg_l[16][512];        // 64 KB gate weights, [iter][tid]
  __shared__ uint2 wat_l[4][512];        // 16 KB att weights, [iter][tid]
  __shared__ unsigned int vl_l[8][512];  // 16 KB Vl bf16 pairs, [iter][tid]
  __shared__ float qT[32][65];           //  8.3 KB qWq^T (own att cols)
  __shared__ __align__(16) float h_lds[DD];
  __shared__ float xsl[SC];
  __shared__ float hw_att[32], waa[32], c_sh[32];
  __shared__ float att_part[16][33];
  __shared__ float sc_part[8][TQL];
  __shared__ float al_s[TQL];
  __shared__ float pre_s[GC], bias_s[GC];

  const float* qv_b = qv + (size_t)b * TQL * NC;
  u64* xch_s_b = xch_s + b * (NS * TQL);
  u64* xch_h_b = xch_h + b * DD;

  // ---- one-time preload: weights + per-batch activations into LDS
  {
    const uint2* gp = gatel + (size_t)j * 16 * 512;
    for (int i = tid; i < 16 * 512; i += 512) wg_l[i >> 9][i & 511] = gp[i];
    const uint2* ap = attl + (size_t)j * 4 * 512;
    for (int i = tid; i < 4 * 512; i += 512) wat_l[i >> 9][i & 511] = ap[i];
    for (int i = tid; i < TQL * 32; i += 512) {
      int tq = i >> 5, a = i & 31;
      qT[a][tq] = qv_b[(size_t)tq * NC + (j << 5) + a];
    }
    // vl_l[ii][slot]: slot -> gcol=slot>>2, gq=slot&3; tw = gq*8+ii
    for (int f = tid; f < 8 * 512; f += 512) {
      int ii = f >> 9, slot = f & 511;
      int gcol = slot >> 2, gq = slot & 3;
      int tw = gq * 8 + ii;
      int g = gcol >> 5, m = (j << 5) + (gcol & 31);
      float v0 = qv_b[(size_t)(2 * tw) * NC + DD + (g << 8) + m];
      float v1 = qv_b[(size_t)(2 * tw + 1) * NC + DD + (g << 8) + m];
      vl_l[ii][slot] = packbf(v0, v1);
    }
    if (tid < 32) { waa[tid] = wa[(j << 5) + tid]; c_sh[tid] = 0.f; }
    if (tid < GC) {
      int g = tid >> 5, m = (j << 5) + (tid & 31);
      bias_s[tid] = (g == 0) ? bias_f[m] : bias_iog[((g - 1) << 8) + m];
    }
  }
  float mq = mask_q[b * TQL + lane];    // softmax mask, lane = tq (wave 0 uses)
  __syncthreads();

  // role indices
  const int ak = tid >> 5;                        // att: 16-way k-split
  const int stq = tid & 63, ssub = tid >> 6;      // scores: 8 subs x 4 cols
  const int gcol = tid >> 2, gq = tid & 3;        // gate/pre: 4-way k/tq split

  for (int t = 0; t < TPL; ++t) {
    const float* xrow = xpl + ((size_t)b * TPL + t) * NC + j * SC;
    float xv = (tid < SC) ? xrow[tid] : 0.f;      // in flight during h wait
    const unsigned int hseq = (unsigned int)(lbase + t);       // h after t-1
    const unsigned int sseq = (unsigned int)(lbase + t + 1);   // this step

    __syncthreads();                   // B0: prev-step LDS reads done
    // ---- spin-load h[t] (poll+gather fused: one LLC round trip)
    if (tid < DD) h_lds[tid] = (t > 0) ? spinload(xch_h_b + tid, hseq) : 0.f;
    if (tid < SC) xsl[tid] = xv;
    __syncthreads();                   // B1: h_lds, xsl ready

    // ---- att GEMV from LDS: 32 cols x 16-way k-split (16 k each)
    {
      float a0 = 0.f, a1 = 0.f;
      #pragma unroll
      for (int i = 0; i < 4; ++i) {
        int kq = ak * 4 + i;
        uint2 w = wat_l[i][tid];
        float4 h0 = *(const float4*)&h_lds[kq * 4];
        a0 = fmaf(h0.x, bflo(w.x), a0); a1 = fmaf(h0.y, bfhi(w.x), a1);
        a0 = fmaf(h0.z, bflo(w.y), a0); a1 = fmaf(h0.w, bfhi(w.y), a1);
      }
      att_part[ak][tid & 31] = a0 + a1;
    }
    __syncthreads();                   // B2
    if (tid < 32) {
      float s = 0.f;
      #pragma unroll
      for (int i = 0; i < 16; ++i) s += att_part[i][tid];
      hw_att[tid] = s;
    }
    __syncthreads();                   // B3: hw_att ready

    // ---- scores: 64 tq x 8 subs (4 a each)
    {
      float p = 0.f;
      #pragma unroll
      for (int i = 0; i < 4; ++i) {
        int a = ssub * 4 + i;
        p = fmaf(fast_tanh(qT[a][stq] + xsl[a] + hw_att[a]), waa[a], p);
      }
      sc_part[ssub][stq] = p;
    }
    __syncthreads();                   // B4
    // ---- publish score partial (wave 0), seq-stamped
    if (tid < TQL) {
      float s = 0.f;
      #pragma unroll
      for (int q = 0; q < 8; ++q) s += sc_part[q][tid];
      astore64(xch_s_b + (j << 6) + tid, packsv(s, sseq));
    }

    // ---- gate GEMV from LDS (all 512): hides score flight
    float hwg;
    {
      float g0 = 0.f, g1 = 0.f;
      #pragma unroll
      for (int i = 0; i < 16; ++i) {
        int kq = i * 4 + gq;                     // interleaved k-split
        uint2 w = wg_l[i][tid];
        float4 h0 = *(const float4*)&h_lds[kq * 4];
        g0 = fmaf(h0.x, bflo(w.x), g0); g1 = fmaf(h0.y, bfhi(w.x), g1);
        g0 = fmaf(h0.z, bflo(w.y), g0); g1 = fmaf(h0.w, bfhi(w.y), g1);
      }
      hwg = g0 + g1;
      hwg += __shfl_xor(hwg, 1);
      hwg += __shfl_xor(hwg, 2);       // all 4 partners hold full hw_gate[gcol]
    }

    // ---- spin-load score partials (all 512, one element each), softmax
    __syncthreads();                   // B5: publisher's sc_part reads done
    sc_part[ssub][stq] = spinload(xch_s_b + (ssub << 6) + stq, sseq);
    __syncthreads();                   // B6
    if (tid < TQL) {
      float v = 0.f;
      #pragma unroll
      for (int q = 0; q < 8; ++q) v += sc_part[q][tid];
      v = (mq > 0.f) ? v : -1e9f;
      float m = v;
      #pragma unroll
      for (int off = 32; off > 0; off >>= 1) m = fmaxf(m, __shfl_xor(m, off));
      float p = __expf(v - m);
      float su = p;
      #pragma unroll
      for (int off = 32; off > 0; off >>= 1) su += __shfl_xor(su, off);
      al_s[tid] = p * __builtin_amdgcn_rcpf(su);
    }
    __syncthreads();                   // B7: al_s ready

    // ---- pre: alpha@Vl (4-way tq split) + hwg + x + bias
    {
      float d0 = 0.f, d1 = 0.f;
      #pragma unroll
      for (int i = 0; i < 8; ++i) {
        int tw = gq * 8 + i;
        unsigned int v = vl_l[i][tid];
        d0 = fmaf(al_s[2 * tw], bflo(v), d0);
        d1 = fmaf(al_s[2 * tw + 1], bfhi(v), d1);
      }
      float d = d0 + d1;
      d += __shfl_xor(d, 1);
      d += __shfl_xor(d, 2);
      if (gq == 0)
        pre_s[gcol] = hwg + d + xsl[32 + gcol] + bias_s[gcol];
    }
    __syncthreads();                   // B8: pre ready

    // ---- gates + state for own 32 h-elems; publish seq-stamped h slice
    if (tid < 32) {
      float f  = pre_s[tid];
      float ii = pre_s[32 + tid];
      float oo = pre_s[64 + tid];
      float g  = pre_s[96 + tid];
      float mtv = mask_p[b * TPL + t];
      int m = (j << 5) + tid;
      float c0 = c_sh[tid], h0 = h_lds[m];
      float c1 = fast_sigmoid(f) * c0 + fast_sigmoid(ii) * fast_tanh(g);
      c1 = c1 * mtv + c0 * (1.f - mtv);
      float h1 = fast_sigmoid(oo) * fast_tanh(c1);
      h1 = h1 * mtv + h0 * (1.f - mtv);
      c_sh[tid] = c1;
      astore64(xch_h_b + m, packsv(h1, (unsigned int)(lbase + t + 1)));
      out[((size_t)b * TPL + t) * DD + m] = h1;
    }
    // no trailing barrier: next iteration's B0 orders h_lds reuse
  }
}

// -----------------------------------------------------------------------------
extern "C" void kernel_launch(void* const* d_in, const int* in_sizes, int n_in,
                              void* d_out, int out_size, void* d_ws, size_t ws_size,
                              hipStream_t stream) {
  const float* input_p  = (const float*)d_in[0];
  const float* mask_p   = (const float*)d_in[1];
  const float* input_q  = (const float*)d_in[2];
  const float* mask_q   = (const float*)d_in[3];
  const float* W_att_p  = (const float*)d_in[4];
  const float* W_att_q  = (const float*)d_in[5];
  const float* W_att_r  = (const float*)d_in[6];
  const float* w_att    = (const float*)d_in[7];
  const float* W_lstm   = (const float*)d_in[8];
  const float* bias_f   = (const float*)d_in[9];
  const float* bias_iog = (const float*)d_in[10];
  float* out = (float*)d_out;
  float* ws  = (float*)d_ws;
  (void)ws_size; (void)in_sizes; (void)n_in; (void)out_size;

  const size_t SZ_XPL  = (size_t)NB * TPL * NC;
  const size_t SZ_QV   = (size_t)NB * TQL * NC;
  const size_t SZ_W    = (size_t)DD * NC;
  const size_t SZ_ATTL = (size_t)NS * 4 * 512;    // uint2 per layer
  const size_t SZ_GATL = (size_t)NS * 16 * 512;   // uint2 per layer

  float* ws_xpl = ws;
  float* ws_qv  = ws_xpl + SZ_XPL;
  float* ws_wx  = ws_qv  + 2 * SZ_QV;
  float* ws_wqv = ws_wx  + 2 * SZ_W;
  float* ws_o0  = ws_wqv + 2 * SZ_W;
  uint2* ws_attl = (uint2*)(ws_o0 + (size_t)NB * TPL * DD);
  uint2* ws_gatl = ws_attl + 2 * SZ_ATTL;
  u64*   ws_xs   = (u64*)(ws_gatl + 2 * SZ_GATL);    // [NB][8][64] seq-stamped
  u64*   ws_xh   = ws_xs + NB * NS * TQL;            // [NB][256]  seq-stamped

  dim3 gpack((DD * NC + 255) / 256, 2);
  pack_weights<<<gpack, 256, 0, stream>>>(W_att_p, W_att_q, W_lstm, ws_wx, ws_wqv);
  pack_attl<<<(2 * NS * 4 * 512 + 255) / 256, 256, 0, stream>>>(W_att_r, ws_attl);
  pack_gatel<<<(2 * NS * 16 * 512 + 255) / 256, 256, 0, stream>>>(W_lstm, ws_gatl);
  hipMemsetAsync(ws_xs, 0, (NB * NS * TQL + NB * DD) * sizeof(u64), stream);

  for (int d = 0; d < 2; ++d) {
    dim3 g(NC / 64, (NB * TQL) / 64);
    sgemm<false><<<g, 256, 0, stream>>>(input_q, ws_wqv + d * SZ_W, ws_qv + d * SZ_QV);
  }

  // layer 0
  {
    dim3 g(NC / 64, (NB * TPL) / 64);
    sgemm<true><<<g, 256, 0, stream>>>(input_p, ws_wx, ws_xpl);
    scan<<<NB * NS, 512, 0, stream>>>(ws_xpl, ws_qv, ws_attl, ws_gatl,
                                      w_att, bias_f, bias_iog, mask_p, mask_q,
                                      ws_xs, ws_xh, ws_o0, 0);
  }
  // layer 1
  {
    dim3 g(NC / 64, (NB * TPL) / 64);
    sgemm<true><<<g, 256, 0, stream>>>(ws_o0, ws_wx + SZ_W, ws_xpl);
    scan<<<NB * NS, 512, 0, stream>>>(ws_xpl, ws_qv + SZ_QV, ws_attl + SZ_ATTL,
                                      ws_gatl + SZ_GATL, w_att + DD, bias_f + DD,
                                      bias_iog + 3 * DD, mask_p, mask_q,
                                      ws_xs, ws_xh, out, TPL);
  }
}